// Round 4
// baseline (781.631 us; speedup 1.0000x reference)
//
#include <hip/hip_runtime.h>
#include <hip/hip_bf16.h>
#include <stdint.h>

// SpikingSelfAttention: out = (q*cumsum_t(k*v)) @ Wp^T + bp, q/k/v = LIF(x@W^T)
// T=4, B=16, N=1024, D=512 -> M = 16384 rows.
//
// Phase 0: pre-split x and W into bf16 hi/lo limb planes (k-step-tiled layout
//          for contiguous staging reads). Memory-bound, done once.
// Phase 1: 2-limb bf16 MFMA qkv GEMM (hh+hl+lh) + fp32 LIF in registers;
//          flag |mem-THR| < TAU into a worklist. Staging is pure copy now.
// Phase 2: exact fp64 recompute of flagged (m,d) trajectories (tiny).
// Phase 3: out = s @ Wp^T + bp as 1-limb bf16 MFMA (s in {0..4} exact bf16).
// Fallback: if ws_size can't hold the limb planes, run the round-3 fused-split
//           qkv kernel instead (identical results, slower).

#define T_ 4
#define M_ 16384
#define D_ 512
#define MT 64
#define DT 32
#define BK 32
#define RS 40        // old fused kernel LDS row stride (u16)
#define RS2 36       // new kernel LDS row stride: 50.7KB total -> 3 blocks/CU
#define TAU 5e-4f

typedef __attribute__((ext_vector_type(8))) short bs8;   // 8 bf16 (4 VGPR)
typedef __attribute__((ext_vector_type(4))) float f32x4; // MFMA C/D
typedef unsigned short u16;

static __device__ __forceinline__ void split1(float f, u16& h, u16& l) {
  __hip_bfloat16 hb = __float2bfloat16(f);           // RTN hi limb
  float hf = __bfloat162float(hb);
  __hip_bfloat16 lb = __float2bfloat16(f - hf);      // RTN lo limb
  h = __builtin_bit_cast(u16, hb);
  l = __builtin_bit_cast(u16, lb);
}
static __device__ __forceinline__ uint32_t pack2(u16 a, u16 b) {
  return (uint32_t)a | ((uint32_t)b << 16);
}
static __device__ __forceinline__ uint32_t packf2(float a, float b) {
  return (__builtin_bit_cast(uint32_t, a) >> 16) |
         (__builtin_bit_cast(uint32_t, b) & 0xFFFF0000u);
}

// ---------------------------------------------------------------------------
__global__ void zero_count(uint32_t* c) { *c = 0; }

// One-time Wp fp32 -> bf16 (RTN), natural [j][k] layout for out_gemm.
__global__ void conv_wp(const float* __restrict__ Wp, u16* __restrict__ wpb) {
  int i = (blockIdx.x * 256 + threadIdx.x) * 8;
  float4 a = *reinterpret_cast<const float4*>(Wp + i);
  float4 b = *reinterpret_cast<const float4*>(Wp + i + 4);
  u16 h[8];
  h[0] = __builtin_bit_cast(u16, __float2bfloat16(a.x));
  h[1] = __builtin_bit_cast(u16, __float2bfloat16(a.y));
  h[2] = __builtin_bit_cast(u16, __float2bfloat16(a.z));
  h[3] = __builtin_bit_cast(u16, __float2bfloat16(a.w));
  h[4] = __builtin_bit_cast(u16, __float2bfloat16(b.x));
  h[5] = __builtin_bit_cast(u16, __float2bfloat16(b.y));
  h[6] = __builtin_bit_cast(u16, __float2bfloat16(b.z));
  h[7] = __builtin_bit_cast(u16, __float2bfloat16(b.w));
  uint4 o;
  o.x = pack2(h[0], h[1]); o.y = pack2(h[2], h[3]);
  o.z = pack2(h[4], h[5]); o.w = pack2(h[6], h[7]);
  *reinterpret_cast<uint4*>(wpb + i) = o;
}

// ---------------------------------------------------------------------------
// Phase 0a: split x into bf16 limb planes, k-step-tiled:
//   plane[((t*16 + ks)*16384 + m)*32 + (k&31)], ks = k>>5.
// grid 16384 x 256, 8 elems/thread. flat bits: k:9 | m:14 | t:2.
// ---------------------------------------------------------------------------
__global__ __launch_bounds__(256)
void xsplit(const float* __restrict__ x, u16* __restrict__ xh,
            u16* __restrict__ xl) {
  size_t flat = ((size_t)blockIdx.x * 256 + threadIdx.x) * 8;
  int k = (int)(flat & 511);
  int m = (int)((flat >> 9) & 16383);
  int t = (int)(flat >> 23);
  float4 a = *reinterpret_cast<const float4*>(x + flat);
  float4 b = *reinterpret_cast<const float4*>(x + flat + 4);
  u16 h[8], l[8];
  split1(a.x,h[0],l[0]); split1(a.y,h[1],l[1]);
  split1(a.z,h[2],l[2]); split1(a.w,h[3],l[3]);
  split1(b.x,h[4],l[4]); split1(b.y,h[5],l[5]);
  split1(b.z,h[6],l[6]); split1(b.w,h[7],l[7]);
  size_t dst = (((size_t)t * 16 + (k >> 5)) * 16384 + m) * 32 + (k & 31);
  uint4 oh = make_uint4(pack2(h[0],h[1]), pack2(h[2],h[3]),
                        pack2(h[4],h[5]), pack2(h[6],h[7]));
  uint4 ol = make_uint4(pack2(l[0],l[1]), pack2(l[2],l[3]),
                        pack2(l[4],l[5]), pack2(l[6],l[7]));
  *reinterpret_cast<uint4*>(xh + dst) = oh;
  *reinterpret_cast<uint4*>(xl + dst) = ol;
}

// Phase 0b: split Wq|Wk|Wv into limb planes, k-step-tiled:
//   plane[((mat*16 + ks)*512 + d)*32 + (k&31)].
// grid 384 x 256. flat bits: k:9 | d:9 | mat:2.
__global__ __launch_bounds__(256)
void wsplit(const float* __restrict__ Wq, const float* __restrict__ Wk,
            const float* __restrict__ Wv, u16* __restrict__ wh,
            u16* __restrict__ wl) {
  size_t flat = ((size_t)blockIdx.x * 256 + threadIdx.x) * 8;
  int k = (int)(flat & 511);
  int d = (int)((flat >> 9) & 511);
  int mat = (int)(flat >> 18);
  const float* wp = (mat == 0) ? Wq : ((mat == 1) ? Wk : Wv);
  size_t src = ((size_t)d << 9) + k;
  float4 a = *reinterpret_cast<const float4*>(wp + src);
  float4 b = *reinterpret_cast<const float4*>(wp + src + 4);
  u16 h[8], l[8];
  split1(a.x,h[0],l[0]); split1(a.y,h[1],l[1]);
  split1(a.z,h[2],l[2]); split1(a.w,h[3],l[3]);
  split1(b.x,h[4],l[4]); split1(b.y,h[5],l[5]);
  split1(b.z,h[6],l[6]); split1(b.w,h[7],l[7]);
  size_t dst = (((size_t)mat * 16 + (k >> 5)) * 512 + d) * 32 + (k & 31);
  uint4 oh = make_uint4(pack2(h[0],h[1]), pack2(h[2],h[3]),
                        pack2(h[4],h[5]), pack2(h[6],h[7]));
  uint4 ol = make_uint4(pack2(l[0],l[1]), pack2(l[2],l[3]),
                        pack2(l[4],l[5]), pack2(l[6],l[7]));
  *reinterpret_cast<uint4*>(wh + dst) = oh;
  *reinterpret_cast<uint4*>(wl + dst) = ol;
}

// ---------------------------------------------------------------------------
// Phase 1 (NEW): qkv GEMM from pre-split limb planes. Staging = pure copy
// (16B load -> 16B LDS write). Fragment/MFMA/LIF identical to proven r3 code.
// ---------------------------------------------------------------------------
__global__ __launch_bounds__(256, 3)
void qkv_mfma_lif2(const u16* __restrict__ xh, const u16* __restrict__ xl,
                   const u16* __restrict__ wh, const u16* __restrict__ wl,
                   uint8_t* __restrict__ s_out,
                   uint32_t* __restrict__ count,
                   uint32_t* __restrict__ list,
                   uint32_t cap) {
  __shared__ u16 Xh[T_][MT][RS2], Xl[T_][MT][RS2];   // 36.9 KB
  __shared__ u16 Wh[3][DT][RS2], Wl[3][DT][RS2];     // 13.8 KB
  const int tid = threadIdx.x;
  const int lane = tid & 63;
  const int w = tid >> 6;
  const int d0 = blockIdx.x * DT;
  const int m0 = blockIdx.y * MT;

  f32x4 acc[T_][3][2];
  #pragma unroll
  for (int t = 0; t < T_; ++t)
    #pragma unroll
    for (int mat = 0; mat < 3; ++mat)
      #pragma unroll
      for (int dh = 0; dh < 2; ++dh) acc[t][mat][dh] = (f32x4)0.0f;

  for (int ks = 0; ks < D_ / BK; ++ks) {
    __syncthreads();
    // Stage X: 2048 16B chunks (4t x 2limb x 64m x 4kc), 8 per thread.
    // Wave reads 1KB contiguous per (t,limb) plane slice.
    #pragma unroll
    for (int c = 0; c < 8; ++c) {
      int idx = c * 256 + tid;
      int c2 = idx & 255, sel = (idx >> 8) & 1, t = idx >> 9;
      int m = c2 >> 2, kc = c2 & 3;
      const u16* src = (sel ? xl : xh) +
          (((size_t)t * 16 + ks) * 16384 + (size_t)(m0 + m)) * 32 + kc * 8;
      uint4 v = *reinterpret_cast<const uint4*>(src);
      u16* dst = sel ? &Xl[t][m][kc * 8] : &Xh[t][m][kc * 8];
      *reinterpret_cast<uint4*>(dst) = v;
    }
    // Stage W: 768 16B chunks (3mat x 2limb x 32d x 4kc), 3 per thread.
    #pragma unroll
    for (int c = 0; c < 3; ++c) {
      int idx = c * 256 + tid;
      int c2 = idx & 127, sel = (idx >> 7) & 1, mat = idx >> 8;
      int dd = c2 >> 2, kc = c2 & 3;
      const u16* src = (sel ? wl : wh) +
          (((size_t)mat * 16 + ks) * 512 + (size_t)(d0 + dd)) * 32 + kc * 8;
      uint4 v = *reinterpret_cast<const uint4*>(src);
      u16* dst = sel ? &Wl[mat][dd][kc * 8] : &Wh[mat][dd][kc * 8];
      *reinterpret_cast<uint4*>(dst) = v;
    }
    __syncthreads();

    bs8 a[T_][2];
    #pragma unroll
    for (int t = 0; t < T_; ++t) {
      a[t][0] = *reinterpret_cast<const bs8*>(&Xh[t][w*16 + (lane&15)][(lane>>4)*8]);
      a[t][1] = *reinterpret_cast<const bs8*>(&Xl[t][w*16 + (lane&15)][(lane>>4)*8]);
    }
    #pragma unroll
    for (int mat = 0; mat < 3; ++mat) {
      bs8 b[2][2];
      #pragma unroll
      for (int dh = 0; dh < 2; ++dh) {
        b[dh][0] = *reinterpret_cast<const bs8*>(&Wh[mat][dh*16 + (lane&15)][(lane>>4)*8]);
        b[dh][1] = *reinterpret_cast<const bs8*>(&Wl[mat][dh*16 + (lane&15)][(lane>>4)*8]);
      }
      #pragma unroll
      for (int t = 0; t < T_; ++t)
        #pragma unroll
        for (int dh = 0; dh < 2; ++dh) {
          acc[t][mat][dh] = __builtin_amdgcn_mfma_f32_16x16x32_bf16(
              a[t][0], b[dh][0], acc[t][mat][dh], 0, 0, 0);
          acc[t][mat][dh] = __builtin_amdgcn_mfma_f32_16x16x32_bf16(
              a[t][0], b[dh][1], acc[t][mat][dh], 0, 0, 0);
          acc[t][mat][dh] = __builtin_amdgcn_mfma_f32_16x16x32_bf16(
              a[t][1], b[dh][0], acc[t][mat][dh], 0, 0, 0);
        }
    }
  }

  const int rbase = w * 16 + ((lane >> 4) << 2);
  const int dd = lane & 15;
  #pragma unroll
  for (int dh = 0; dh < 2; ++dh) {
    const int gd = d0 + dh * 16 + dd;
    #pragma unroll
    for (int r = 0; r < 4; ++r) {
      const int gm = m0 + rbase + r;
      float mq = 0.f, mk = 0.f, mv = 0.f;
      int ctx = 0; bool flag = false;
      #pragma unroll
      for (int t = 0; t < T_; ++t) {
        mq = mq * 0.9f + acc[t][0][dh][r];
        mk = mk * 0.9f + acc[t][1][dh][r];
        mv = mv * 0.9f + acc[t][2][dh][r];
        flag |= (fabsf(mq - 1.f) < TAU) || (fabsf(mk - 1.f) < TAU) ||
                (fabsf(mv - 1.f) < TAU);
        int sq = (mq >= 1.f); int sk = (mk >= 1.f); int sv = (mv >= 1.f);
        mq -= (float)sq; mk -= (float)sk; mv -= (float)sv;
        ctx += sk & sv;
        s_out[(size_t)t * (M_ * (size_t)D_) + (size_t)gm * D_ + gd] =
            (uint8_t)(sq ? ctx : 0);
      }
      if (flag) {
        uint32_t pos = atomicAdd(count, 1u);
        if (pos < cap) list[pos] = ((uint32_t)gm << 9) | (uint32_t)gd;
      }
    }
  }
}

// ---------------------------------------------------------------------------
// Phase 1 FALLBACK (round-3 verbatim): fused-split qkv, used if ws too small.
// ---------------------------------------------------------------------------
__global__ __launch_bounds__(256, 2)
void qkv_mfma_lif(const float* __restrict__ x,
                  const float* __restrict__ Wq,
                  const float* __restrict__ Wk,
                  const float* __restrict__ Wv,
                  uint8_t* __restrict__ s_out,
                  uint32_t* __restrict__ count,
                  uint32_t* __restrict__ list,
                  uint32_t cap) {
  __shared__ u16 Xh[T_][MT][RS], Xl[T_][MT][RS];
  __shared__ u16 Wh[3][DT][RS], Wl[3][DT][RS];
  const int tid = threadIdx.x;
  const int lane = tid & 63;
  const int w = tid >> 6;
  const int d0 = blockIdx.x * DT;
  const int m0 = blockIdx.y * MT;

  f32x4 acc[T_][3][2];
  #pragma unroll
  for (int t = 0; t < T_; ++t)
    #pragma unroll
    for (int mat = 0; mat < 3; ++mat)
      #pragma unroll
      for (int dh = 0; dh < 2; ++dh) acc[t][mat][dh] = (f32x4)0.0f;

  for (int k0 = 0; k0 < D_; k0 += BK) {
    __syncthreads();
    #pragma unroll
    for (int c = 0; c < 8; ++c) {
      int idx = c * 256 + tid;
      int k4 = idx & 7, row = idx >> 3;
      int t = row >> 6, m = row & 63;
      float4 f = *reinterpret_cast<const float4*>(
          x + ((size_t)t * M_ + (size_t)(m0 + m)) * D_ + k0 + k4 * 4);
      u16 h0,h1,h2,h3,l0,l1,l2,l3;
      split1(f.x,h0,l0); split1(f.y,h1,l1); split1(f.z,h2,l2); split1(f.w,h3,l3);
      *reinterpret_cast<uint2*>(&Xh[t][m][k4*4]) = make_uint2(pack2(h0,h1), pack2(h2,h3));
      *reinterpret_cast<uint2*>(&Xl[t][m][k4*4]) = make_uint2(pack2(l0,l1), pack2(l2,l3));
    }
    #pragma unroll
    for (int c = 0; c < 3; ++c) {
      int idx = c * 256 + tid;
      int k4 = idx & 7, row = idx >> 3;
      int mat = row >> 5, dd = row & 31;
      const float* wp = (mat == 0) ? Wq : ((mat == 1) ? Wk : Wv);
      float4 f = *reinterpret_cast<const float4*>(
          wp + (size_t)(d0 + dd) * D_ + k0 + k4 * 4);
      u16 h0,h1,h2,h3,l0,l1,l2,l3;
      split1(f.x,h0,l0); split1(f.y,h1,l1); split1(f.z,h2,l2); split1(f.w,h3,l3);
      *reinterpret_cast<uint2*>(&Wh[mat][dd][k4*4]) = make_uint2(pack2(h0,h1), pack2(h2,h3));
      *reinterpret_cast<uint2*>(&Wl[mat][dd][k4*4]) = make_uint2(pack2(l0,l1), pack2(l2,l3));
    }
    __syncthreads();

    bs8 a[T_][2];
    #pragma unroll
    for (int t = 0; t < T_; ++t) {
      a[t][0] = *reinterpret_cast<const bs8*>(&Xh[t][w*16 + (lane&15)][(lane>>4)*8]);
      a[t][1] = *reinterpret_cast<const bs8*>(&Xl[t][w*16 + (lane&15)][(lane>>4)*8]);
    }
    #pragma unroll
    for (int mat = 0; mat < 3; ++mat) {
      bs8 b[2][2];
      #pragma unroll
      for (int dh = 0; dh < 2; ++dh) {
        b[dh][0] = *reinterpret_cast<const bs8*>(&Wh[mat][dh*16 + (lane&15)][(lane>>4)*8]);
        b[dh][1] = *reinterpret_cast<const bs8*>(&Wl[mat][dh*16 + (lane&15)][(lane>>4)*8]);
      }
      #pragma unroll
      for (int t = 0; t < T_; ++t)
        #pragma unroll
        for (int dh = 0; dh < 2; ++dh) {
          acc[t][mat][dh] = __builtin_amdgcn_mfma_f32_16x16x32_bf16(
              a[t][0], b[dh][0], acc[t][mat][dh], 0, 0, 0);
          acc[t][mat][dh] = __builtin_amdgcn_mfma_f32_16x16x32_bf16(
              a[t][0], b[dh][1], acc[t][mat][dh], 0, 0, 0);
          acc[t][mat][dh] = __builtin_amdgcn_mfma_f32_16x16x32_bf16(
              a[t][1], b[dh][0], acc[t][mat][dh], 0, 0, 0);
        }
    }
  }

  const int rbase = w * 16 + ((lane >> 4) << 2);
  const int dd = lane & 15;
  #pragma unroll
  for (int dh = 0; dh < 2; ++dh) {
    const int gd = d0 + dh * 16 + dd;
    #pragma unroll
    for (int r = 0; r < 4; ++r) {
      const int gm = m0 + rbase + r;
      float mq = 0.f, mk = 0.f, mv = 0.f;
      int ctx = 0; bool flag = false;
      #pragma unroll
      for (int t = 0; t < T_; ++t) {
        mq = mq * 0.9f + acc[t][0][dh][r];
        mk = mk * 0.9f + acc[t][1][dh][r];
        mv = mv * 0.9f + acc[t][2][dh][r];
        flag |= (fabsf(mq - 1.f) < TAU) || (fabsf(mk - 1.f) < TAU) ||
                (fabsf(mv - 1.f) < TAU);
        int sq = (mq >= 1.f); int sk = (mk >= 1.f); int sv = (mv >= 1.f);
        mq -= (float)sq; mk -= (float)sk; mv -= (float)sv;
        ctx += sk & sv;
        s_out[(size_t)t * (M_ * (size_t)D_) + (size_t)gm * D_ + gd] =
            (uint8_t)(sq ? ctx : 0);
      }
      if (flag) {
        uint32_t pos = atomicAdd(count, 1u);
        if (pos < cap) list[pos] = ((uint32_t)gm << 9) | (uint32_t)gd;
      }
    }
  }
}

// ---------------------------------------------------------------------------
// Phase 2: exact fp64 recompute of flagged trajectories.
// ---------------------------------------------------------------------------
__global__ __launch_bounds__(64, 8)
void fix_borderline(const float* __restrict__ x,
                    const float* __restrict__ Wq,
                    const float* __restrict__ Wk,
                    const float* __restrict__ Wv,
                    uint8_t* __restrict__ s_out,
                    const uint32_t* __restrict__ count,
                    const uint32_t* __restrict__ list,
                    uint32_t cap) {
  uint32_t n = *count; if (n > cap) n = cap;
  const int lane = threadIdx.x;
  for (uint32_t j = blockIdx.x; j < n; j += gridDim.x) {
    uint32_t e = list[j];
    int m = (int)(e >> 9), d = (int)(e & 511);
    const int kb = lane * 8;
    float xr[T_][8], wr[3][8];
    #pragma unroll
    for (int t = 0; t < T_; ++t) {
      float4 a = *reinterpret_cast<const float4*>(x + ((size_t)t*M_ + m)*D_ + kb);
      float4 b = *reinterpret_cast<const float4*>(x + ((size_t)t*M_ + m)*D_ + kb + 4);
      xr[t][0]=a.x; xr[t][1]=a.y; xr[t][2]=a.z; xr[t][3]=a.w;
      xr[t][4]=b.x; xr[t][5]=b.y; xr[t][6]=b.z; xr[t][7]=b.w;
    }
    #pragma unroll
    for (int mat = 0; mat < 3; ++mat) {
      const float* wp = (mat == 0) ? Wq : ((mat == 1) ? Wk : Wv);
      float4 a = *reinterpret_cast<const float4*>(wp + (size_t)d*D_ + kb);
      float4 b = *reinterpret_cast<const float4*>(wp + (size_t)d*D_ + kb + 4);
      wr[mat][0]=a.x; wr[mat][1]=a.y; wr[mat][2]=a.z; wr[mat][3]=a.w;
      wr[mat][4]=b.x; wr[mat][5]=b.y; wr[mat][6]=b.z; wr[mat][7]=b.w;
    }
    double pd[T_][3];
    #pragma unroll
    for (int t = 0; t < T_; ++t)
      #pragma unroll
      for (int mat = 0; mat < 3; ++mat) {
        double s = 0.0;
        #pragma unroll
        for (int i = 0; i < 8; ++i) s += (double)xr[t][i] * (double)wr[mat][i];
        pd[t][mat] = s;
      }
    #pragma unroll
    for (int off = 32; off > 0; off >>= 1)
      #pragma unroll
      for (int t = 0; t < T_; ++t)
        #pragma unroll
        for (int mat = 0; mat < 3; ++mat)
          pd[t][mat] += __shfl_xor(pd[t][mat], off);
    double mq = 0.0, mk = 0.0, mv = 0.0;
    int ctx = 0; uint8_t sv4[T_];
    #pragma unroll
    for (int t = 0; t < T_; ++t) {
      mq = mq * 0.9 + pd[t][0];
      mk = mk * 0.9 + pd[t][1];
      mv = mv * 0.9 + pd[t][2];
      int sq = (mq >= 1.0); int sk = (mk >= 1.0); int sv = (mv >= 1.0);
      mq -= (double)sq; mk -= (double)sk; mv -= (double)sv;
      ctx += sk & sv;
      sv4[t] = (uint8_t)(sq ? ctx : 0);
    }
    if (lane < T_)
      s_out[(size_t)lane * (M_ * (size_t)D_) + (size_t)m * D_ + d] = sv4[lane];
  }
}

// ---------------------------------------------------------------------------
// Phase 3: out = s @ Wp^T + bp via bf16 MFMA (round-3 proven).
// ---------------------------------------------------------------------------
__global__ __launch_bounds__(256, 4)
void out_gemm_mfma(const uint8_t* __restrict__ s,
                   const u16* __restrict__ wpb,
                   const float* __restrict__ bp,
                   float* __restrict__ out) {
  __shared__ u16 As[128][BK];
  __shared__ u16 Bs[64][BK];
  const int tid = threadIdx.x;
  const int lane = tid & 63;
  const int w = tid >> 6;
  const int j0 = blockIdx.x * 64;
  const int r0 = blockIdx.y * 128;

  f32x4 acc[2][4];
  #pragma unroll
  for (int rg = 0; rg < 2; ++rg)
    #pragma unroll
    for (int jf = 0; jf < 4; ++jf) acc[rg][jf] = (f32x4)0.0f;

  for (int k0 = 0; k0 < D_; k0 += BK) {
    __syncthreads();
    {
      int row = tid >> 1, half = tid & 1;
      uint4 u = *reinterpret_cast<const uint4*>(
          s + (size_t)(r0 + row) * D_ + k0 + half * 16);
      uint32_t dw[4] = {u.x, u.y, u.z, u.w};
      uint32_t pk[8];
      #pragma unroll
      for (int q = 0; q < 4; ++q) {
        uint32_t v = dw[q];
        float f0 = (float)(v & 0xff);
        float f1 = (float)((v >> 8) & 0xff);
        float f2 = (float)((v >> 16) & 0xff);
        float f3 = (float)(v >> 24);
        pk[q*2+0] = packf2(f0, f1);
        pk[q*2+1] = packf2(f2, f3);
      }
      uint4* dst = reinterpret_cast<uint4*>(&As[row][half * 16]);
      dst[0] = make_uint4(pk[0], pk[1], pk[2], pk[3]);
      dst[1] = make_uint4(pk[4], pk[5], pk[6], pk[7]);
    }
    {
      int row = tid >> 2, q = tid & 3;
      uint4 u = *reinterpret_cast<const uint4*>(
          wpb + (size_t)(j0 + row) * D_ + k0 + q * 8);
      *reinterpret_cast<uint4*>(&Bs[row][q * 8]) = u;
    }
    __syncthreads();

    const int rb = w * 32;
    bs8 a0 = *reinterpret_cast<const bs8*>(&As[rb      + (lane&15)][(lane>>4)*8]);
    bs8 a1 = *reinterpret_cast<const bs8*>(&As[rb + 16 + (lane&15)][(lane>>4)*8]);
    #pragma unroll
    for (int jf = 0; jf < 4; ++jf) {
      bs8 b = *reinterpret_cast<const bs8*>(&Bs[jf*16 + (lane&15)][(lane>>4)*8]);
      acc[0][jf] = __builtin_amdgcn_mfma_f32_16x16x32_bf16(a0, b, acc[0][jf], 0, 0, 0);
      acc[1][jf] = __builtin_amdgcn_mfma_f32_16x16x32_bf16(a1, b, acc[1][jf], 0, 0, 0);
    }
  }

  const int col = lane & 15;
  const int rloc = (lane >> 4) * 4;
  #pragma unroll
  for (int jf = 0; jf < 4; ++jf) {
    float bv = bp[j0 + jf * 16 + col];
    #pragma unroll
    for (int rg = 0; rg < 2; ++rg) {
      #pragma unroll
      for (int reg = 0; reg < 4; ++reg) {
        out[(size_t)(r0 + w * 32 + rg * 16 + rloc + reg) * D_ +
            j0 + jf * 16 + col] = acc[rg][jf][reg] + bv;
      }
    }
  }
}

extern "C" void kernel_launch(void* const* d_in, const int* in_sizes, int n_in,
                              void* d_out, int out_size, void* d_ws, size_t ws_size,
                              hipStream_t stream) {
  const float* x  = (const float*)d_in[0];
  const float* Wq = (const float*)d_in[1];
  const float* Wk = (const float*)d_in[2];
  const float* Wv = (const float*)d_in[3];
  const float* Wp = (const float*)d_in[4];
  const float* bp = (const float*)d_in[5];
  float* out = (float*)d_out;

  // ws layout:
  //   s u8 (32MB) | wpb bf16 (512KB) | count (64B) | list (4MB) |
  //   [full path only:] Xh (64MB) | Xl (64MB) | Wh (1.5MB) | Wl (1.5MB)
  const size_t s_bytes    = (size_t)T_ * M_ * D_;            // 33554432
  const size_t wp_bytes   = (size_t)D_ * D_ * sizeof(u16);   // 524288
  const size_t list_bytes = (size_t)4 << 20;                 // 4 MiB
  const size_t xp_bytes   = (size_t)T_ * M_ * D_ * sizeof(u16);  // 64 MiB
  const size_t wl_bytes   = (size_t)3 * D_ * D_ * sizeof(u16);   // 1.5 MiB

  char* p = (char*)d_ws;
  uint8_t*  s_ws  = (uint8_t*)p;              p += s_bytes;
  u16*      wpb   = (u16*)p;                  p += wp_bytes;
  uint32_t* count = (uint32_t*)p;             p += 64;
  uint32_t* list  = (uint32_t*)p;             p += list_bytes;
  size_t head = (size_t)(p - (char*)d_ws);
  uint32_t cap = (uint32_t)(list_bytes / sizeof(uint32_t));
  if (ws_size < head) {  // extremely defensive; round 1 proved >= 64 MiB
    cap = 0;
  }

  const size_t need_full = head + 2 * xp_bytes + 2 * wl_bytes;

  zero_count<<<1, 1, 0, stream>>>(count);
  conv_wp<<<dim3(128), dim3(256), 0, stream>>>(Wp, wpb);

  if (ws_size >= need_full) {
    u16* xh = (u16*)p;                        p += xp_bytes;
    u16* xl = (u16*)p;                        p += xp_bytes;
    u16* wh = (u16*)p;                        p += wl_bytes;
    u16* wl = (u16*)p;
    xsplit<<<dim3(16384), dim3(256), 0, stream>>>(x, xh, xl);
    wsplit<<<dim3(384), dim3(256), 0, stream>>>(Wq, Wk, Wv, wh, wl);
    qkv_mfma_lif2<<<dim3(D_/DT, M_/MT), dim3(256), 0, stream>>>(
        xh, xl, wh, wl, s_ws, count, list, cap);
  } else {
    qkv_mfma_lif<<<dim3(D_/DT, M_/MT), dim3(256), 0, stream>>>(
        x, Wq, Wk, Wv, s_ws, count, list, cap);
  }
  fix_borderline<<<dim3(1024), dim3(64), 0, stream>>>(
      x, Wq, Wk, Wv, s_ws, count, list, cap);
  out_gemm_mfma<<<dim3(D_/64, (T_*M_)/128), dim3(256), 0, stream>>>(
      s_ws, wpb, bp, out);
}

// Round 5
// 636.366 us; speedup vs baseline: 1.2283x; 1.2283x over previous
//
#include <hip/hip_runtime.h>
#include <hip/hip_bf16.h>
#include <stdint.h>

// SpikingSelfAttention: out = (q*cumsum_t(k*v)) @ Wp^T + bp, q/k/v = LIF(x@W^T)
// T=4, B=16, N=1024, D=512 -> M = 16384 rows.
//
// Phase 0: pre-split x,W into bf16 hi/lo limb planes (k-step-tiled).
// Phase 1: qkv GEMM as ONE K=1536 segmented bf16-MFMA stream
//          (seg0 xh*wh, seg1 xl*wh, seg2 xh*wl = hh+lh+hl), double-buffered
//          LDS, issue-early/write-late pipeline (T14), one barrier/iter,
//          bijective XCD swizzle (T1). fp32 LIF in registers; |mem-1|<TAU
//          flagged to a worklist.
// Phase 2: exact fp64 recompute of flagged (m,d) trajectories.
// Phase 3: out = s @ Wp^T + bp as 1-limb bf16 MFMA (s exact in bf16).

#define T_ 4
#define M_ 16384
#define D_ 512
#define MT 64
#define DT 32
#define BK 32
#define RS 40        // fallback kernel LDS row stride (u16)
#define RS2 36       // pipelined kernel LDS row stride (proven conflict-free)
#define TAU 5e-4f
#define NKS 48       // K=1536 view: 48 steps of 32

typedef __attribute__((ext_vector_type(8))) short bs8;
typedef __attribute__((ext_vector_type(4))) float f32x4;
typedef unsigned short u16;

static __device__ __forceinline__ void split1(float f, u16& h, u16& l) {
  __hip_bfloat16 hb = __float2bfloat16(f);
  float hf = __bfloat162float(hb);
  __hip_bfloat16 lb = __float2bfloat16(f - hf);
  h = __builtin_bit_cast(u16, hb);
  l = __builtin_bit_cast(u16, lb);
}
static __device__ __forceinline__ uint32_t pack2(u16 a, u16 b) {
  return (uint32_t)a | ((uint32_t)b << 16);
}
static __device__ __forceinline__ uint32_t packf2(float a, float b) {
  return (__builtin_bit_cast(uint32_t, a) >> 16) |
         (__builtin_bit_cast(uint32_t, b) & 0xFFFF0000u);
}

// ---------------------------------------------------------------------------
__global__ void zero_count(uint32_t* c) { *c = 0; }

__global__ void conv_wp(const float* __restrict__ Wp, u16* __restrict__ wpb) {
  int i = (blockIdx.x * 256 + threadIdx.x) * 8;
  float4 a = *reinterpret_cast<const float4*>(Wp + i);
  float4 b = *reinterpret_cast<const float4*>(Wp + i + 4);
  u16 h[8];
  h[0] = __builtin_bit_cast(u16, __float2bfloat16(a.x));
  h[1] = __builtin_bit_cast(u16, __float2bfloat16(a.y));
  h[2] = __builtin_bit_cast(u16, __float2bfloat16(a.z));
  h[3] = __builtin_bit_cast(u16, __float2bfloat16(a.w));
  h[4] = __builtin_bit_cast(u16, __float2bfloat16(b.x));
  h[5] = __builtin_bit_cast(u16, __float2bfloat16(b.y));
  h[6] = __builtin_bit_cast(u16, __float2bfloat16(b.z));
  h[7] = __builtin_bit_cast(u16, __float2bfloat16(b.w));
  uint4 o;
  o.x = pack2(h[0], h[1]); o.y = pack2(h[2], h[3]);
  o.z = pack2(h[4], h[5]); o.w = pack2(h[6], h[7]);
  *reinterpret_cast<uint4*>(wpb + i) = o;
}

// ---------------------------------------------------------------------------
// Phase 0a: split x into bf16 limb planes, k-step-tiled:
//   plane[((t*16 + ks)*16384 + m)*32 + (k&31)].
// ---------------------------------------------------------------------------
__global__ __launch_bounds__(256)
void xsplit(const float* __restrict__ x, u16* __restrict__ xh,
            u16* __restrict__ xl) {
  size_t flat = ((size_t)blockIdx.x * 256 + threadIdx.x) * 8;
  int k = (int)(flat & 511);
  int m = (int)((flat >> 9) & 16383);
  int t = (int)(flat >> 23);
  float4 a = *reinterpret_cast<const float4*>(x + flat);
  float4 b = *reinterpret_cast<const float4*>(x + flat + 4);
  u16 h[8], l[8];
  split1(a.x,h[0],l[0]); split1(a.y,h[1],l[1]);
  split1(a.z,h[2],l[2]); split1(a.w,h[3],l[3]);
  split1(b.x,h[4],l[4]); split1(b.y,h[5],l[5]);
  split1(b.z,h[6],l[6]); split1(b.w,h[7],l[7]);
  size_t dst = (((size_t)t * 16 + (k >> 5)) * 16384 + m) * 32 + (k & 31);
  uint4 oh = make_uint4(pack2(h[0],h[1]), pack2(h[2],h[3]),
                        pack2(h[4],h[5]), pack2(h[6],h[7]));
  uint4 ol = make_uint4(pack2(l[0],l[1]), pack2(l[2],l[3]),
                        pack2(l[4],l[5]), pack2(l[6],l[7]));
  *reinterpret_cast<uint4*>(xh + dst) = oh;
  *reinterpret_cast<uint4*>(xl + dst) = ol;
}

// Phase 0b: W limb planes: plane[((mat*16 + ks)*512 + d)*32 + (k&31)].
__global__ __launch_bounds__(256)
void wsplit(const float* __restrict__ Wq, const float* __restrict__ Wk,
            const float* __restrict__ Wv, u16* __restrict__ wh,
            u16* __restrict__ wl) {
  size_t flat = ((size_t)blockIdx.x * 256 + threadIdx.x) * 8;
  int k = (int)(flat & 511);
  int d = (int)((flat >> 9) & 511);
  int mat = (int)(flat >> 18);
  const float* wp = (mat == 0) ? Wq : ((mat == 1) ? Wk : Wv);
  size_t src = ((size_t)d << 9) + k;
  float4 a = *reinterpret_cast<const float4*>(wp + src);
  float4 b = *reinterpret_cast<const float4*>(wp + src + 4);
  u16 h[8], l[8];
  split1(a.x,h[0],l[0]); split1(a.y,h[1],l[1]);
  split1(a.z,h[2],l[2]); split1(a.w,h[3],l[3]);
  split1(b.x,h[4],l[4]); split1(b.y,h[5],l[5]);
  split1(b.z,h[6],l[6]); split1(b.w,h[7],l[7]);
  size_t dst = (((size_t)mat * 16 + (k >> 5)) * 512 + d) * 32 + (k & 31);
  uint4 oh = make_uint4(pack2(h[0],h[1]), pack2(h[2],h[3]),
                        pack2(h[4],h[5]), pack2(h[6],h[7]));
  uint4 ol = make_uint4(pack2(l[0],l[1]), pack2(l[2],l[3]),
                        pack2(l[4],l[5]), pack2(l[6],l[7]));
  *reinterpret_cast<uint4*>(wh + dst) = oh;
  *reinterpret_cast<uint4*>(wl + dst) = ol;
}

// ---------------------------------------------------------------------------
// Phase 1 (NEW): pipelined qkv GEMM over the K=1536 segmented stream.
// Per k-step seg = ks/16: A-plane = (seg==1 ? xl : xh), B-plane =
// (seg==2 ? wl : wh) -> accumulates hh + lh + hl into the same fp32 acc.
// Double-buffered LDS, one barrier per iter, loads for ks+1 issued before
// the MFMAs of ks and written to LDS after them (T14).
// ---------------------------------------------------------------------------
__global__ __launch_bounds__(256, 3)
void qkv_mfma_lif3(const u16* __restrict__ xh, const u16* __restrict__ xl,
                   const u16* __restrict__ wh, const u16* __restrict__ wl,
                   uint8_t* __restrict__ s_out,
                   uint32_t* __restrict__ count,
                   uint32_t* __restrict__ list,
                   uint32_t cap) {
  __shared__ u16 Xs[2][T_][MT][RS2];   // 36.9 KB
  __shared__ u16 Wsh[2][3][DT][RS2];   // 13.8 KB   (total 50.7 KB -> 3/CU)
  const int tid = threadIdx.x;
  const int lane = tid & 63;
  const int w = tid >> 6;

  // Bijective XCD swizzle: all 16 d-blocks of one m-tile on one XCD.
  // s = xcd + 8*q, q = cc*16 + j, c = xcd + 8*cc. 4096 = 8*512 exact.
  const int sblk = blockIdx.x;
  const int xcd = sblk & 7, q = sblk >> 3;
  const int c_mt = xcd + 8 * (q >> 4);   // m-tile [0,256)
  const int jdb = q & 15;                // d-block [0,16)
  const int d0 = jdb * DT;
  const int m0 = c_mt * MT;

  f32x4 acc[T_][3][2];
  #pragma unroll
  for (int t = 0; t < T_; ++t)
    #pragma unroll
    for (int mat = 0; mat < 3; ++mat)
      #pragma unroll
      for (int dh = 0; dh < 2; ++dh) acc[t][mat][dh] = (f32x4)0.0f;

  // Staging registers: one k-step tile in flight.
  uint4 ra[4];   // A: 4t x 64m x 32k bf16 = 16KB = 1024 x 16B, 4/thread
  uint2 rb[3];   // B: 3mat x 32d x 32k bf16 = 6KB = 768 x 8B, 3/thread

  // Per-thread staging coordinates (compile-time unrolled over c).
#define ISSUE(ks_)                                                           \
  {                                                                          \
    int seg = (ks_) >> 4, kk = (ks_) & 15;                                   \
    const u16* xsrc = (seg == 1) ? xl : xh;                                  \
    _Pragma("unroll")                                                        \
    for (int c = 0; c < 4; ++c) {                                            \
      int idx = c * 256 + tid;                                               \
      int t = idx >> 8, r = idx & 255;                                       \
      int m = r >> 2, kc = r & 3;                                            \
      ra[c] = *reinterpret_cast<const uint4*>(                               \
          xsrc + (((size_t)t * 16 + kk) * 16384 + m0 + m) * 32 + kc * 8);    \
    }                                                                        \
    const u16* wsrc = (seg == 2) ? wl : wh;                                  \
    _Pragma("unroll")                                                        \
    for (int c = 0; c < 3; ++c) {                                            \
      int idx = c * 256 + tid;                                               \
      int mat = idx >> 8, r = idx & 255;                                     \
      int dd = r >> 3, kq = r & 7;                                           \
      rb[c] = *reinterpret_cast<const uint2*>(                               \
          wsrc + (((size_t)mat * 16 + kk) * 512 + d0 + dd) * 32 + kq * 4);   \
    }                                                                        \
  }

#define STORE(buf_)                                                          \
  {                                                                          \
    _Pragma("unroll")                                                        \
    for (int c = 0; c < 4; ++c) {                                            \
      int idx = c * 256 + tid;                                               \
      int t = idx >> 8, r = idx & 255;                                       \
      int m = r >> 2, kc = r & 3;                                            \
      *reinterpret_cast<uint4*>(&Xs[buf_][t][m][kc * 8]) = ra[c];            \
    }                                                                        \
    _Pragma("unroll")                                                        \
    for (int c = 0; c < 3; ++c) {                                            \
      int idx = c * 256 + tid;                                               \
      int mat = idx >> 8, r = idx & 255;                                     \
      int dd = r >> 3, kq = r & 7;                                           \
      *reinterpret_cast<uint2*>(&Wsh[buf_][mat][dd][kq * 4]) = rb[c];        \
    }                                                                        \
  }

  ISSUE(0);
  STORE(0);
  __syncthreads();

  for (int ks = 0; ks < NKS; ++ks) {
    const int buf = ks & 1;
    if (ks + 1 < NKS) ISSUE(ks + 1);           // loads in flight during MFMA

    bs8 a[T_];
    #pragma unroll
    for (int t = 0; t < T_; ++t)
      a[t] = *reinterpret_cast<const bs8*>(
          &Xs[buf][t][w * 16 + (lane & 15)][(lane >> 4) * 8]);
    #pragma unroll
    for (int mat = 0; mat < 3; ++mat) {
      bs8 b0 = *reinterpret_cast<const bs8*>(
          &Wsh[buf][mat][(lane & 15)][(lane >> 4) * 8]);
      bs8 b1 = *reinterpret_cast<const bs8*>(
          &Wsh[buf][mat][16 + (lane & 15)][(lane >> 4) * 8]);
      #pragma unroll
      for (int t = 0; t < T_; ++t) {
        acc[t][mat][0] = __builtin_amdgcn_mfma_f32_16x16x32_bf16(
            a[t], b0, acc[t][mat][0], 0, 0, 0);
        acc[t][mat][1] = __builtin_amdgcn_mfma_f32_16x16x32_bf16(
            a[t], b1, acc[t][mat][1], 0, 0, 0);
      }
    }

    if (ks + 1 < NKS) STORE(buf ^ 1);          // vmcnt wait lands here
    __syncthreads();
  }
#undef ISSUE
#undef STORE

  // In-register LIF (identical to proven r3/r4 epilogue).
  const int rbase = w * 16 + ((lane >> 4) << 2);
  const int dd = lane & 15;
  #pragma unroll
  for (int dh = 0; dh < 2; ++dh) {
    const int gd = d0 + dh * 16 + dd;
    #pragma unroll
    for (int r = 0; r < 4; ++r) {
      const int gm = m0 + rbase + r;
      float mq = 0.f, mk = 0.f, mv = 0.f;
      int ctx = 0; bool flag = false;
      #pragma unroll
      for (int t = 0; t < T_; ++t) {
        mq = mq * 0.9f + acc[t][0][dh][r];
        mk = mk * 0.9f + acc[t][1][dh][r];
        mv = mv * 0.9f + acc[t][2][dh][r];
        flag |= (fabsf(mq - 1.f) < TAU) || (fabsf(mk - 1.f) < TAU) ||
                (fabsf(mv - 1.f) < TAU);
        int sq = (mq >= 1.f); int sk = (mk >= 1.f); int sv = (mv >= 1.f);
        mq -= (float)sq; mk -= (float)sk; mv -= (float)sv;
        ctx += sk & sv;
        s_out[(size_t)t * (M_ * (size_t)D_) + (size_t)gm * D_ + gd] =
            (uint8_t)(sq ? ctx : 0);
      }
      if (flag) {
        uint32_t pos = atomicAdd(count, 1u);
        if (pos < cap) list[pos] = ((uint32_t)gm << 9) | (uint32_t)gd;
      }
    }
  }
}

// ---------------------------------------------------------------------------
// Phase 1 FALLBACK (round-3 verbatim, fused split): used only if ws too small.
// ---------------------------------------------------------------------------
__global__ __launch_bounds__(256, 2)
void qkv_mfma_lif(const float* __restrict__ x,
                  const float* __restrict__ Wq,
                  const float* __restrict__ Wk,
                  const float* __restrict__ Wv,
                  uint8_t* __restrict__ s_out,
                  uint32_t* __restrict__ count,
                  uint32_t* __restrict__ list,
                  uint32_t cap) {
  __shared__ u16 Xh[T_][MT][RS], Xl[T_][MT][RS];
  __shared__ u16 Wh[3][DT][RS], Wl[3][DT][RS];
  const int tid = threadIdx.x;
  const int lane = tid & 63;
  const int w = tid >> 6;
  const int d0 = blockIdx.x * DT;
  const int m0 = blockIdx.y * MT;

  f32x4 acc[T_][3][2];
  #pragma unroll
  for (int t = 0; t < T_; ++t)
    #pragma unroll
    for (int mat = 0; mat < 3; ++mat)
      #pragma unroll
      for (int dh = 0; dh < 2; ++dh) acc[t][mat][dh] = (f32x4)0.0f;

  for (int k0 = 0; k0 < D_; k0 += BK) {
    __syncthreads();
    #pragma unroll
    for (int c = 0; c < 8; ++c) {
      int idx = c * 256 + tid;
      int k4 = idx & 7, row = idx >> 3;
      int t = row >> 6, m = row & 63;
      float4 f = *reinterpret_cast<const float4*>(
          x + ((size_t)t * M_ + (size_t)(m0 + m)) * D_ + k0 + k4 * 4);
      u16 h0,h1,h2,h3,l0,l1,l2,l3;
      split1(f.x,h0,l0); split1(f.y,h1,l1); split1(f.z,h2,l2); split1(f.w,h3,l3);
      *reinterpret_cast<uint2*>(&Xh[t][m][k4*4]) = make_uint2(pack2(h0,h1), pack2(h2,h3));
      *reinterpret_cast<uint2*>(&Xl[t][m][k4*4]) = make_uint2(pack2(l0,l1), pack2(l2,l3));
    }
    #pragma unroll
    for (int c = 0; c < 3; ++c) {
      int idx = c * 256 + tid;
      int k4 = idx & 7, row = idx >> 3;
      int mat = row >> 5, dd = row & 31;
      const float* wp = (mat == 0) ? Wq : ((mat == 1) ? Wk : Wv);
      float4 f = *reinterpret_cast<const float4*>(
          wp + (size_t)(d0 + dd) * D_ + k0 + k4 * 4);
      u16 h0,h1,h2,h3,l0,l1,l2,l3;
      split1(f.x,h0,l0); split1(f.y,h1,l1); split1(f.z,h2,l2); split1(f.w,h3,l3);
      *reinterpret_cast<uint2*>(&Wh[mat][dd][k4*4]) = make_uint2(pack2(h0,h1), pack2(h2,h3));
      *reinterpret_cast<uint2*>(&Wl[mat][dd][k4*4]) = make_uint2(pack2(l0,l1), pack2(l2,l3));
    }
    __syncthreads();

    bs8 a[T_][2];
    #pragma unroll
    for (int t = 0; t < T_; ++t) {
      a[t][0] = *reinterpret_cast<const bs8*>(&Xh[t][w*16 + (lane&15)][(lane>>4)*8]);
      a[t][1] = *reinterpret_cast<const bs8*>(&Xl[t][w*16 + (lane&15)][(lane>>4)*8]);
    }
    #pragma unroll
    for (int mat = 0; mat < 3; ++mat) {
      bs8 b[2][2];
      #pragma unroll
      for (int dh = 0; dh < 2; ++dh) {
        b[dh][0] = *reinterpret_cast<const bs8*>(&Wh[mat][dh*16 + (lane&15)][(lane>>4)*8]);
        b[dh][1] = *reinterpret_cast<const bs8*>(&Wl[mat][dh*16 + (lane&15)][(lane>>4)*8]);
      }
      #pragma unroll
      for (int t = 0; t < T_; ++t)
        #pragma unroll
        for (int dh = 0; dh < 2; ++dh) {
          acc[t][mat][dh] = __builtin_amdgcn_mfma_f32_16x16x32_bf16(
              a[t][0], b[dh][0], acc[t][mat][dh], 0, 0, 0);
          acc[t][mat][dh] = __builtin_amdgcn_mfma_f32_16x16x32_bf16(
              a[t][0], b[dh][1], acc[t][mat][dh], 0, 0, 0);
          acc[t][mat][dh] = __builtin_amdgcn_mfma_f32_16x16x32_bf16(
              a[t][1], b[dh][0], acc[t][mat][dh], 0, 0, 0);
        }
    }
  }

  const int rbase = w * 16 + ((lane >> 4) << 2);
  const int dd = lane & 15;
  #pragma unroll
  for (int dh = 0; dh < 2; ++dh) {
    const int gd = d0 + dh * 16 + dd;
    #pragma unroll
    for (int r = 0; r < 4; ++r) {
      const int gm = m0 + rbase + r;
      float mq = 0.f, mk = 0.f, mv = 0.f;
      int ctx = 0; bool flag = false;
      #pragma unroll
      for (int t = 0; t < T_; ++t) {
        mq = mq * 0.9f + acc[t][0][dh][r];
        mk = mk * 0.9f + acc[t][1][dh][r];
        mv = mv * 0.9f + acc[t][2][dh][r];
        flag |= (fabsf(mq - 1.f) < TAU) || (fabsf(mk - 1.f) < TAU) ||
                (fabsf(mv - 1.f) < TAU);
        int sq = (mq >= 1.f); int sk = (mk >= 1.f); int sv = (mv >= 1.f);
        mq -= (float)sq; mk -= (float)sk; mv -= (float)sv;
        ctx += sk & sv;
        s_out[(size_t)t * (M_ * (size_t)D_) + (size_t)gm * D_ + gd] =
            (uint8_t)(sq ? ctx : 0);
      }
      if (flag) {
        uint32_t pos = atomicAdd(count, 1u);
        if (pos < cap) list[pos] = ((uint32_t)gm << 9) | (uint32_t)gd;
      }
    }
  }
}

// ---------------------------------------------------------------------------
// Phase 2: exact fp64 recompute of flagged trajectories.
// ---------------------------------------------------------------------------
__global__ __launch_bounds__(64, 8)
void fix_borderline(const float* __restrict__ x,
                    const float* __restrict__ Wq,
                    const float* __restrict__ Wk,
                    const float* __restrict__ Wv,
                    uint8_t* __restrict__ s_out,
                    const uint32_t* __restrict__ count,
                    const uint32_t* __restrict__ list,
                    uint32_t cap) {
  uint32_t n = *count; if (n > cap) n = cap;
  const int lane = threadIdx.x;
  for (uint32_t j = blockIdx.x; j < n; j += gridDim.x) {
    uint32_t e = list[j];
    int m = (int)(e >> 9), d = (int)(e & 511);
    const int kb = lane * 8;
    float xr[T_][8], wr[3][8];
    #pragma unroll
    for (int t = 0; t < T_; ++t) {
      float4 a = *reinterpret_cast<const float4*>(x + ((size_t)t*M_ + m)*D_ + kb);
      float4 b = *reinterpret_cast<const float4*>(x + ((size_t)t*M_ + m)*D_ + kb + 4);
      xr[t][0]=a.x; xr[t][1]=a.y; xr[t][2]=a.z; xr[t][3]=a.w;
      xr[t][4]=b.x; xr[t][5]=b.y; xr[t][6]=b.z; xr[t][7]=b.w;
    }
    #pragma unroll
    for (int mat = 0; mat < 3; ++mat) {
      const float* wp = (mat == 0) ? Wq : ((mat == 1) ? Wk : Wv);
      float4 a = *reinterpret_cast<const float4*>(wp + (size_t)d*D_ + kb);
      float4 b = *reinterpret_cast<const float4*>(wp + (size_t)d*D_ + kb + 4);
      wr[mat][0]=a.x; wr[mat][1]=a.y; wr[mat][2]=a.z; wr[mat][3]=a.w;
      wr[mat][4]=b.x; wr[mat][5]=b.y; wr[mat][6]=b.z; wr[mat][7]=b.w;
    }
    double pd[T_][3];
    #pragma unroll
    for (int t = 0; t < T_; ++t)
      #pragma unroll
      for (int mat = 0; mat < 3; ++mat) {
        double s = 0.0;
        #pragma unroll
        for (int i = 0; i < 8; ++i) s += (double)xr[t][i] * (double)wr[mat][i];
        pd[t][mat] = s;
      }
    #pragma unroll
    for (int off = 32; off > 0; off >>= 1)
      #pragma unroll
      for (int t = 0; t < T_; ++t)
        #pragma unroll
        for (int mat = 0; mat < 3; ++mat)
          pd[t][mat] += __shfl_xor(pd[t][mat], off);
    double mq = 0.0, mk = 0.0, mv = 0.0;
    int ctx = 0; uint8_t sv4[T_];
    #pragma unroll
    for (int t = 0; t < T_; ++t) {
      mq = mq * 0.9 + pd[t][0];
      mk = mk * 0.9 + pd[t][1];
      mv = mv * 0.9 + pd[t][2];
      int sq = (mq >= 1.0); int sk = (mk >= 1.0); int sv = (mv >= 1.0);
      mq -= (double)sq; mk -= (double)sk; mv -= (double)sv;
      ctx += sk & sv;
      sv4[t] = (uint8_t)(sq ? ctx : 0);
    }
    if (lane < T_)
      s_out[(size_t)lane * (M_ * (size_t)D_) + (size_t)m * D_ + d] = sv4[lane];
  }
}

// ---------------------------------------------------------------------------
// Phase 3: out = s @ Wp^T + bp via bf16 MFMA (round-3 proven).
// ---------------------------------------------------------------------------
__global__ __launch_bounds__(256, 4)
void out_gemm_mfma(const uint8_t* __restrict__ s,
                   const u16* __restrict__ wpb,
                   const float* __restrict__ bp,
                   float* __restrict__ out) {
  __shared__ u16 As[128][BK];
  __shared__ u16 Bs[64][BK];
  const int tid = threadIdx.x;
  const int lane = tid & 63;
  const int w = tid >> 6;
  const int j0 = blockIdx.x * 64;
  const int r0 = blockIdx.y * 128;

  f32x4 acc[2][4];
  #pragma unroll
  for (int rg = 0; rg < 2; ++rg)
    #pragma unroll
    for (int jf = 0; jf < 4; ++jf) acc[rg][jf] = (f32x4)0.0f;

  for (int k0 = 0; k0 < D_; k0 += BK) {
    __syncthreads();
    {
      int row = tid >> 1, half = tid & 1;
      uint4 u = *reinterpret_cast<const uint4*>(
          s + (size_t)(r0 + row) * D_ + k0 + half * 16);
      uint32_t dw[4] = {u.x, u.y, u.z, u.w};
      uint32_t pk[8];
      #pragma unroll
      for (int qq = 0; qq < 4; ++qq) {
        uint32_t v = dw[qq];
        float f0 = (float)(v & 0xff);
        float f1 = (float)((v >> 8) & 0xff);
        float f2 = (float)((v >> 16) & 0xff);
        float f3 = (float)(v >> 24);
        pk[qq*2+0] = packf2(f0, f1);
        pk[qq*2+1] = packf2(f2, f3);
      }
      uint4* dst = reinterpret_cast<uint4*>(&As[row][half * 16]);
      dst[0] = make_uint4(pk[0], pk[1], pk[2], pk[3]);
      dst[1] = make_uint4(pk[4], pk[5], pk[6], pk[7]);
    }
    {
      int row = tid >> 2, qq = tid & 3;
      uint4 u = *reinterpret_cast<const uint4*>(
          wpb + (size_t)(j0 + row) * D_ + k0 + qq * 8);
      *reinterpret_cast<uint4*>(&Bs[row][qq * 8]) = u;
    }
    __syncthreads();

    const int rb = w * 32;
    bs8 a0 = *reinterpret_cast<const bs8*>(&As[rb      + (lane&15)][(lane>>4)*8]);
    bs8 a1 = *reinterpret_cast<const bs8*>(&As[rb + 16 + (lane&15)][(lane>>4)*8]);
    #pragma unroll
    for (int jf = 0; jf < 4; ++jf) {
      bs8 b = *reinterpret_cast<const bs8*>(&Bs[jf*16 + (lane&15)][(lane>>4)*8]);
      acc[0][jf] = __builtin_amdgcn_mfma_f32_16x16x32_bf16(a0, b, acc[0][jf], 0, 0, 0);
      acc[1][jf] = __builtin_amdgcn_mfma_f32_16x16x32_bf16(a1, b, acc[1][jf], 0, 0, 0);
    }
  }

  const int col = lane & 15;
  const int rloc = (lane >> 4) * 4;
  #pragma unroll
  for (int jf = 0; jf < 4; ++jf) {
    float bv = bp[j0 + jf * 16 + col];
    #pragma unroll
    for (int rg = 0; rg < 2; ++rg) {
      #pragma unroll
      for (int reg = 0; reg < 4; ++reg) {
        out[(size_t)(r0 + w * 32 + rg * 16 + rloc + reg) * D_ +
            j0 + jf * 16 + col] = acc[rg][jf][reg] + bv;
      }
    }
  }
}

extern "C" void kernel_launch(void* const* d_in, const int* in_sizes, int n_in,
                              void* d_out, int out_size, void* d_ws, size_t ws_size,
                              hipStream_t stream) {
  const float* x  = (const float*)d_in[0];
  const float* Wq = (const float*)d_in[1];
  const float* Wk = (const float*)d_in[2];
  const float* Wv = (const float*)d_in[3];
  const float* Wp = (const float*)d_in[4];
  const float* bp = (const float*)d_in[5];
  float* out = (float*)d_out;

  const size_t s_bytes    = (size_t)T_ * M_ * D_;                // 32 MiB
  const size_t wp_bytes   = (size_t)D_ * D_ * sizeof(u16);       // 512 KiB
  const size_t list_bytes = (size_t)4 << 20;                     // 4 MiB
  const size_t xp_bytes   = (size_t)T_ * M_ * D_ * sizeof(u16);  // 64 MiB
  const size_t wl_bytes   = (size_t)3 * D_ * D_ * sizeof(u16);   // 1.5 MiB

  char* p = (char*)d_ws;
  uint8_t*  s_ws  = (uint8_t*)p;              p += s_bytes;
  u16*      wpb   = (u16*)p;                  p += wp_bytes;
  uint32_t* count = (uint32_t*)p;             p += 64;
  uint32_t* list  = (uint32_t*)p;             p += list_bytes;
  size_t head = (size_t)(p - (char*)d_ws);
  uint32_t cap = (uint32_t)(list_bytes / sizeof(uint32_t));
  if (ws_size < head) cap = 0;

  const size_t need_full = head + 2 * xp_bytes + 2 * wl_bytes;

  zero_count<<<1, 1, 0, stream>>>(count);
  conv_wp<<<dim3(128), dim3(256), 0, stream>>>(Wp, wpb);

  if (ws_size >= need_full) {
    u16* xhp = (u16*)p;                       p += xp_bytes;
    u16* xlp = (u16*)p;                       p += xp_bytes;
    u16* whp = (u16*)p;                       p += wl_bytes;
    u16* wlp = (u16*)p;
    xsplit<<<dim3(16384), dim3(256), 0, stream>>>(x, xhp, xlp);
    wsplit<<<dim3(384), dim3(256), 0, stream>>>(Wq, Wk, Wv, whp, wlp);
    qkv_mfma_lif3<<<dim3(4096), dim3(256), 0, stream>>>(
        xhp, xlp, whp, wlp, s_ws, count, list, cap);
  } else {
    qkv_mfma_lif<<<dim3(D_/DT, M_/MT), dim3(256), 0, stream>>>(
        x, Wq, Wk, Wv, s_ws, count, list, cap);
  }
  fix_borderline<<<dim3(1024), dim3(64), 0, stream>>>(
      x, Wq, Wk, Wv, s_ws, count, list, cap);
  out_gemm_mfma<<<dim3(D_/64, (T_*M_)/128), dim3(256), 0, stream>>>(
      s_ws, wpb, bp, out);
}